// Round 1
// baseline (580.026 us; speedup 1.0000x reference)
//
#include <hip/hip_runtime.h>

// N=4, C=64 (per input), C2=128, H=W=256, HW=65536
// y (dwconv output) is staged in d_out (exactly 4*128*65536 floats = out_size).
// ws layout: stats[1024] floats (mean,rstd per (n,c2)), then flow[4*262144] floats
// (4 planes [o][n*HW]).

__device__ __forceinline__ float gelu_exact(float x) {
    return 0.5f * x * (1.0f + erff(x * 0.7071067811865475f));
}

// ---------------- K1: depthwise 5x5 conv + bias + per-plane stats ----------------
__global__ __launch_bounds__(256) void k_dwconv_stats(
    const float* __restrict__ x1, const float* __restrict__ x2,
    const float* __restrict__ dww, const float* __restrict__ dwb,
    float* __restrict__ y, float* __restrict__ stats)
{
    const int bid = blockIdx.x;          // n*128 + c2
    const int n   = bid >> 7;
    const int c2  = bid & 127;
    const int t   = threadIdx.x;
    const float* src = (c2 < 64)
        ? x1 + ((size_t)(n * 64 + c2) << 16)
        : x2 + ((size_t)(n * 64 + (c2 - 64)) << 16);

    float wv[25];
#pragma unroll
    for (int i = 0; i < 25; ++i) wv[i] = dww[c2 * 25 + i];
    const float bias = dwb[c2];

    // ring buffer of 8 rows, 260 valid cols (halo 2 each side), padded to 264
    __shared__ __align__(16) float rows[8][264];

    auto load4 = [&](int rbase) {
        for (int i = t; i < 1040; i += 256) {
            int r   = rbase + i / 260;
            int j   = i % 260;
            int col = j - 2;
            float v = 0.0f;
            if (r >= 0 && r < 256 && col >= 0 && col < 256)
                v = src[(r << 8) + col];
            rows[r & 7][j] = v;
        }
    };

    load4(-2);   // rows -2..1 (negative rows are zero padding)

    float* yo = y + ((size_t)bid << 16);
    const int q  = t & 63;   // column group: cols 4q..4q+3
    const int rr = t >> 6;   // row offset within 4-row group
    float s1 = 0.0f, s2 = 0.0f;

    for (int hb = 0; hb < 256; hb += 4) {
        __syncthreads();
        load4(hb + 2);       // rows hb+2..hb+5
        __syncthreads();
        const int h = hb + rr;
        float a0 = bias, a1 = bias, a2 = bias, a3 = bias;
#pragma unroll
        for (int dy = 0; dy < 5; ++dy) {
            const float* R = &rows[(h - 2 + dy) & 7][q << 2];
            float4 A = *(const float4*)R;
            float4 B = *(const float4*)(R + 4);
            const float w0 = wv[dy*5+0], w1 = wv[dy*5+1], w2 = wv[dy*5+2],
                        w3 = wv[dy*5+3], w4 = wv[dy*5+4];
            a0 = fmaf(w0, A.x, a0); a0 = fmaf(w1, A.y, a0); a0 = fmaf(w2, A.z, a0);
            a0 = fmaf(w3, A.w, a0); a0 = fmaf(w4, B.x, a0);
            a1 = fmaf(w0, A.y, a1); a1 = fmaf(w1, A.z, a1); a1 = fmaf(w2, A.w, a1);
            a1 = fmaf(w3, B.x, a1); a1 = fmaf(w4, B.y, a1);
            a2 = fmaf(w0, A.z, a2); a2 = fmaf(w1, A.w, a2); a2 = fmaf(w2, B.x, a2);
            a2 = fmaf(w3, B.y, a2); a2 = fmaf(w4, B.z, a2);
            a3 = fmaf(w0, A.w, a3); a3 = fmaf(w1, B.x, a3); a3 = fmaf(w2, B.y, a3);
            a3 = fmaf(w3, B.z, a3); a3 = fmaf(w4, B.w, a3);
        }
        *(float4*)(yo + (h << 8) + (q << 2)) = make_float4(a0, a1, a2, a3);
        s1 += a0 + a1 + a2 + a3;
        s2 = fmaf(a0, a0, s2); s2 = fmaf(a1, a1, s2);
        s2 = fmaf(a2, a2, s2); s2 = fmaf(a3, a3, s2);
    }

    // block reduction (4 waves of 64)
#pragma unroll
    for (int off = 32; off > 0; off >>= 1) {
        s1 += __shfl_down(s1, off);
        s2 += __shfl_down(s2, off);
    }
    __shared__ float red[8];
    const int wave = t >> 6;
    if ((t & 63) == 0) { red[wave] = s1; red[4 + wave] = s2; }
    __syncthreads();
    if (t == 0) {
        float a = red[0] + red[1] + red[2] + red[3];
        float b = red[4] + red[5] + red[6] + red[7];
        float mean = a * (1.0f / 65536.0f);
        float var  = b * (1.0f / 65536.0f) - mean * mean;
        stats[bid * 2]     = mean;
        stats[bid * 2 + 1] = rsqrtf(var + 1e-5f);
    }
}

// ---------------- K2: instance-norm + GELU + 1x1 conv -> flow ----------------
__global__ __launch_bounds__(256) void k_flow(
    const float* __restrict__ y, const float* __restrict__ stats,
    const float* __restrict__ pww, float* __restrict__ flow)
{
    const int bid = blockIdx.x;            // 256 blocks, 64 per n
    const int n   = bid >> 6;
    const int t   = threadIdx.x;
    const int p4  = ((bid & 63) << 8) | t; // float4 index within n-plane [0,16384)

    __shared__ float sm[128], sr[128], spw[512];
    if (t < 128) {
        sm[t] = stats[(n * 128 + t) * 2];
        sr[t] = stats[(n * 128 + t) * 2 + 1];
    } else {
        const int i = t - 128;
        spw[i]       = pww[i];
        spw[i + 128] = pww[i + 128];
        spw[i + 256] = pww[i + 256];
        spw[i + 384] = pww[i + 384];
    }
    __syncthreads();

    const float4* y4 = (const float4*)y + (((size_t)n * 128) << 14) + p4;
    float4 f0 = make_float4(0,0,0,0), f1 = f0, f2 = f0, f3 = f0;
    for (int c = 0; c < 128; ++c) {
        float4 v = y4[(size_t)c << 14];
        const float m = sm[c], rs = sr[c];
        const float g0 = gelu_exact((v.x - m) * rs);
        const float g1 = gelu_exact((v.y - m) * rs);
        const float g2 = gelu_exact((v.z - m) * rs);
        const float g3 = gelu_exact((v.w - m) * rs);
        float w;
        w = spw[c];       f0.x = fmaf(w, g0, f0.x); f0.y = fmaf(w, g1, f0.y);
                          f0.z = fmaf(w, g2, f0.z); f0.w = fmaf(w, g3, f0.w);
        w = spw[128 + c]; f1.x = fmaf(w, g0, f1.x); f1.y = fmaf(w, g1, f1.y);
                          f1.z = fmaf(w, g2, f1.z); f1.w = fmaf(w, g3, f1.w);
        w = spw[256 + c]; f2.x = fmaf(w, g0, f2.x); f2.y = fmaf(w, g1, f2.y);
                          f2.z = fmaf(w, g2, f2.z); f2.w = fmaf(w, g3, f2.w);
        w = spw[384 + c]; f3.x = fmaf(w, g0, f3.x); f3.y = fmaf(w, g1, f3.y);
                          f3.z = fmaf(w, g2, f3.z); f3.w = fmaf(w, g3, f3.w);
    }
    float4* F = (float4*)flow;
    const int fi = (n << 14) + p4;         // float4 units within plane o
    F[fi]           = f0;
    F[65536 + fi]   = f1;
    F[131072 + fi]  = f2;
    F[196608 + fi]  = f3;
}

// ---------------- K3: bilinear warp + subtract ----------------
__global__ __launch_bounds__(256) void k_warp(
    const float* __restrict__ x1, const float* __restrict__ x2,
    const float* __restrict__ flow, float* __restrict__ out)
{
    const int bid = blockIdx.x;            // 1024 blocks, 256 per n
    const int n   = bid >> 8;
    const int t   = threadIdx.x;
    const int p   = ((bid & 255) << 8) | t;
    const int h   = p >> 8, w = p & 255;
    const int np  = (n << 16) | p;

    const float fx1 = flow[np];
    const float fy1 = flow[262144 + np];
    const float fx2 = flow[524288 + np];
    const float fy2 = flow[786432 + np];
    const float S = 255.0f / 512.0f;       // (W-1)/(2W)

    float gxa = (float)w + fx1 * S, gya = (float)h + fy1 * S;
    float gxb = (float)w + fx2 * S, gyb = (float)h + fy2 * S;

    int a00, a01, a10, a11, b00, b01, b10, b11;
    float wa00, wa01, wa10, wa11, wb00, wb01, wb10, wb11;

    {
        float x0f = floorf(gxa), y0f = floorf(gya);
        float wx1 = gxa - x0f, wy1 = gya - y0f;
        float wx0 = 1.0f - wx1, wy0 = 1.0f - wy1;
        int ix0 = (int)x0f, iy0 = (int)y0f;
        int ix1 = ix0 + 1,  iy1 = iy0 + 1;
        bool vx0 = (ix0 >= 0) && (ix0 <= 255), vx1 = (ix1 >= 0) && (ix1 <= 255);
        bool vy0 = (iy0 >= 0) && (iy0 <= 255), vy1 = (iy1 >= 0) && (iy1 <= 255);
        int x0c = min(max(ix0, 0), 255), x1c = min(max(ix1, 0), 255);
        int y0c = min(max(iy0, 0), 255), y1c = min(max(iy1, 0), 255);
        a00 = (y0c << 8) | x0c; a01 = (y0c << 8) | x1c;
        a10 = (y1c << 8) | x0c; a11 = (y1c << 8) | x1c;
        wa00 = wx0 * wy0 * ((vx0 && vy0) ? 1.0f : 0.0f);
        wa01 = wx1 * wy0 * ((vx1 && vy0) ? 1.0f : 0.0f);
        wa10 = wx0 * wy1 * ((vx0 && vy1) ? 1.0f : 0.0f);
        wa11 = wx1 * wy1 * ((vx1 && vy1) ? 1.0f : 0.0f);
    }
    {
        float x0f = floorf(gxb), y0f = floorf(gyb);
        float wx1 = gxb - x0f, wy1 = gyb - y0f;
        float wx0 = 1.0f - wx1, wy0 = 1.0f - wy1;
        int ix0 = (int)x0f, iy0 = (int)y0f;
        int ix1 = ix0 + 1,  iy1 = iy0 + 1;
        bool vx0 = (ix0 >= 0) && (ix0 <= 255), vx1 = (ix1 >= 0) && (ix1 <= 255);
        bool vy0 = (iy0 >= 0) && (iy0 <= 255), vy1 = (iy1 >= 0) && (iy1 <= 255);
        int x0c = min(max(ix0, 0), 255), x1c = min(max(ix1, 0), 255);
        int y0c = min(max(iy0, 0), 255), y1c = min(max(iy1, 0), 255);
        b00 = (y0c << 8) | x0c; b01 = (y0c << 8) | x1c;
        b10 = (y1c << 8) | x0c; b11 = (y1c << 8) | x1c;
        wb00 = wx0 * wy0 * ((vx0 && vy0) ? 1.0f : 0.0f);
        wb01 = wx1 * wy0 * ((vx1 && vy0) ? 1.0f : 0.0f);
        wb10 = wx0 * wy1 * ((vx0 && vy1) ? 1.0f : 0.0f);
        wb11 = wx1 * wy1 * ((vx1 && vy1) ? 1.0f : 0.0f);
    }

    const float* P1 = x1 + (((size_t)n * 64) << 16);
    const float* P2 = x2 + (((size_t)n * 64) << 16);
    float* O1 = out + (((size_t)n * 64) << 16) + p;
    float* O2 = out + 16777216 + (((size_t)n * 64) << 16) + p;

#pragma unroll 4
    for (int c = 0; c < 64; ++c) {
        const size_t base = (size_t)c << 16;
        const float* q1 = P1 + base;
        const float* q2 = P2 + base;
        float sA = wa00 * q1[a00] + wa01 * q1[a01] + wa10 * q1[a10] + wa11 * q1[a11];
        float sB = wb00 * q2[b00] + wb01 * q2[b01] + wb10 * q2[b10] + wb11 * q2[b11];
        O1[base] = sA - q2[p];
        O2[base] = sB - q1[p];
    }
}

extern "C" void kernel_launch(void* const* d_in, const int* in_sizes, int n_in,
                              void* d_out, int out_size, void* d_ws, size_t ws_size,
                              hipStream_t stream) {
    const float* x1  = (const float*)d_in[0];
    const float* x2  = (const float*)d_in[1];
    const float* dww = (const float*)d_in[2];
    const float* dwb = (const float*)d_in[3];
    const float* pww = (const float*)d_in[4];
    float* out = (float*)d_out;

    float* wsf   = (float*)d_ws;
    float* stats = wsf;            // 1024 floats
    float* flow  = wsf + 1024;     // 4*262144 floats (4 MB)
    float* y     = out;            // stage dwconv output in d_out (freed by K3 overwrite)

    k_dwconv_stats<<<512, 256, 0, stream>>>(x1, x2, dww, dwb, y, stats);
    k_flow<<<256, 256, 0, stream>>>(y, stats, pww, flow);
    k_warp<<<1024, 256, 0, stream>>>(x1, x2, flow, out);
}

// Round 2
// 420.692 us; speedup vs baseline: 1.3787x; 1.3787x over previous
//
#include <hip/hip_runtime.h>

// N=4, C=64 (per input), C2=128, H=W=256, HW=65536
// y (dwconv output) staged in d_out (4*128*65536 floats = out_size exactly);
// K2 fully drains y->flow before K3 overwrites d_out.
// ws layout (floats): stats[1024] | flow[4*262144] | part[2*8192]

__device__ __forceinline__ float gelu_exact(float x) {
    return 0.5f * x * (1.0f + erff(x * 0.7071067811865475f));
}

// ---------------- K1: depthwise 5x5 conv + bias + per-tile partial stats ----------------
// grid = 512 planes * 16 tiles; block = 256; one 16-row output tile per block.
__global__ __launch_bounds__(256) void k_dwconv(
    const float* __restrict__ x1, const float* __restrict__ x2,
    const float* __restrict__ dww, const float* __restrict__ dwb,
    float* __restrict__ y, float* __restrict__ part)
{
    const int bid   = blockIdx.x;
    const int plane = bid >> 4;          // n*128 + c2
    const int tile  = bid & 15;
    const int n     = plane >> 7;
    const int c2    = plane & 127;
    const int t     = threadIdx.x;
    const int R0    = tile << 4;         // first output row of this tile

    const float* src = (c2 < 64)
        ? x1 + ((size_t)(n * 64 + c2) << 16)
        : x2 + ((size_t)(n * 64 + (c2 - 64)) << 16);

    float wv[25];
#pragma unroll
    for (int i = 0; i < 25; ++i) wv[i] = dww[c2 * 25 + i];
    const float bias = dwb[c2];

    // 20 input rows (16 + 2 halo each side), col c stored at [c+2]; cols 0,1,258,259 = zero pad
    __shared__ __align__(16) float rows[20][264];

    if (t < 80) {                        // zero the 4 halo columns of all 20 rows
        const int r = t >> 2, k = t & 3;
        rows[r][(k < 2) ? k : 256 + k] = 0.0f;
    }
    // interior: 20 rows * 64 float4 = 1280 vector loads, 5 per thread
#pragma unroll
    for (int k = 0; k < 5; ++k) {
        const int i  = t + (k << 8);     // 0..1279
        const int r  = i >> 6;           // 0..19
        const int g  = i & 63;           // float4 group in row
        const int gr = R0 - 2 + r;       // global input row
        float4 v = make_float4(0.f, 0.f, 0.f, 0.f);
        if (gr >= 0 && gr < 256) v = *(const float4*)(src + (gr << 8) + (g << 2));
        float2* dst = (float2*)&rows[r][2 + (g << 2)];   // 8B-aligned
        dst[0] = make_float2(v.x, v.y);
        dst[1] = make_float2(v.z, v.w);
    }
    __syncthreads();

    float* yo = y + ((size_t)plane << 16);
    const int q  = t & 63;               // column group: cols 4q..4q+3
    const int rr = t >> 6;               // row within 4-row group
    float s1 = 0.0f, s2 = 0.0f;

#pragma unroll
    for (int it = 0; it < 4; ++it) {
        const int lr = rr + (it << 2);   // local output row 0..15
        float a0 = bias, a1 = bias, a2 = bias, a3 = bias;
#pragma unroll
        for (int dy = 0; dy < 5; ++dy) {
            const float* R = &rows[lr + dy][q << 2];     // [4q] = col 4q-2 (16B aligned)
            float4 A = *(const float4*)R;
            float4 B = *(const float4*)(R + 4);
            const float w0 = wv[dy*5+0], w1 = wv[dy*5+1], w2 = wv[dy*5+2],
                        w3 = wv[dy*5+3], w4 = wv[dy*5+4];
            a0 = fmaf(w0, A.x, a0); a0 = fmaf(w1, A.y, a0); a0 = fmaf(w2, A.z, a0);
            a0 = fmaf(w3, A.w, a0); a0 = fmaf(w4, B.x, a0);
            a1 = fmaf(w0, A.y, a1); a1 = fmaf(w1, A.z, a1); a1 = fmaf(w2, A.w, a1);
            a1 = fmaf(w3, B.x, a1); a1 = fmaf(w4, B.y, a1);
            a2 = fmaf(w0, A.z, a2); a2 = fmaf(w1, A.w, a2); a2 = fmaf(w2, B.x, a2);
            a2 = fmaf(w3, B.y, a2); a2 = fmaf(w4, B.z, a2);
            a3 = fmaf(w0, A.w, a3); a3 = fmaf(w1, B.x, a3); a3 = fmaf(w2, B.y, a3);
            a3 = fmaf(w3, B.z, a3); a3 = fmaf(w4, B.w, a3);
        }
        *(float4*)(yo + ((R0 + lr) << 8) + (q << 2)) = make_float4(a0, a1, a2, a3);
        s1 += a0 + a1 + a2 + a3;
        s2 = fmaf(a0, a0, s2); s2 = fmaf(a1, a1, s2);
        s2 = fmaf(a2, a2, s2); s2 = fmaf(a3, a3, s2);
    }

#pragma unroll
    for (int off = 32; off > 0; off >>= 1) {
        s1 += __shfl_down(s1, off);
        s2 += __shfl_down(s2, off);
    }
    __shared__ float red[8];
    const int wave = t >> 6;
    if ((t & 63) == 0) { red[wave] = s1; red[4 + wave] = s2; }
    __syncthreads();
    if (t == 0) {
        part[tile * 512 + plane]        = red[0] + red[1] + red[2] + red[3];
        part[8192 + tile * 512 + plane] = red[4] + red[5] + red[6] + red[7];
    }
}

// ---------------- K1b: finalize per-plane mean/rstd ----------------
__global__ __launch_bounds__(256) void k_stats(
    const float* __restrict__ part, float* __restrict__ stats)
{
    const int p = blockIdx.x * 256 + threadIdx.x;   // 0..511
    float a = 0.0f, b = 0.0f;
#pragma unroll
    for (int tl = 0; tl < 16; ++tl) {
        a += part[tl * 512 + p];
        b += part[8192 + tl * 512 + p];
    }
    const float mean = a * (1.0f / 65536.0f);
    const float var  = b * (1.0f / 65536.0f) - mean * mean;
    stats[2 * p]     = mean;
    stats[2 * p + 1] = rsqrtf(var + 1e-5f);
}

// ---------------- K2: instance-norm + GELU + 1x1 conv -> flow ----------------
__global__ __launch_bounds__(256) void k_flow(
    const float* __restrict__ y, const float* __restrict__ stats,
    const float* __restrict__ pww, float* __restrict__ flow)
{
    const int bid = blockIdx.x;            // 256 blocks, 64 per n
    const int n   = bid >> 6;
    const int t   = threadIdx.x;
    const int p4  = ((bid & 63) << 8) | t; // float4 index within n-plane [0,16384)

    __shared__ float sm[128], sr[128], spw[512];
    if (t < 128) {
        sm[t] = stats[(n * 128 + t) * 2];
        sr[t] = stats[(n * 128 + t) * 2 + 1];
    } else {
        const int i = t - 128;
        spw[i]       = pww[i];
        spw[i + 128] = pww[i + 128];
        spw[i + 256] = pww[i + 256];
        spw[i + 384] = pww[i + 384];
    }
    __syncthreads();

    const float4* y4 = (const float4*)y + (((size_t)n * 128) << 14) + p4;
    float4 f0 = make_float4(0,0,0,0), f1 = f0, f2 = f0, f3 = f0;
#pragma unroll 4
    for (int c = 0; c < 128; ++c) {
        float4 v = y4[(size_t)c << 14];
        const float m = sm[c], rs = sr[c];
        const float g0 = gelu_exact((v.x - m) * rs);
        const float g1 = gelu_exact((v.y - m) * rs);
        const float g2 = gelu_exact((v.z - m) * rs);
        const float g3 = gelu_exact((v.w - m) * rs);
        float w;
        w = spw[c];       f0.x = fmaf(w, g0, f0.x); f0.y = fmaf(w, g1, f0.y);
                          f0.z = fmaf(w, g2, f0.z); f0.w = fmaf(w, g3, f0.w);
        w = spw[128 + c]; f1.x = fmaf(w, g0, f1.x); f1.y = fmaf(w, g1, f1.y);
                          f1.z = fmaf(w, g2, f1.z); f1.w = fmaf(w, g3, f1.w);
        w = spw[256 + c]; f2.x = fmaf(w, g0, f2.x); f2.y = fmaf(w, g1, f2.y);
                          f2.z = fmaf(w, g2, f2.z); f2.w = fmaf(w, g3, f2.w);
        w = spw[384 + c]; f3.x = fmaf(w, g0, f3.x); f3.y = fmaf(w, g1, f3.y);
                          f3.z = fmaf(w, g2, f3.z); f3.w = fmaf(w, g3, f3.w);
    }
    float4* F = (float4*)flow;
    const int fi = (n << 14) + p4;
    F[fi]          = f0;
    F[65536 + fi]  = f1;
    F[131072 + fi] = f2;
    F[196608 + fi] = f3;
}

// ---------------- K3: bilinear warp + subtract ----------------
// grid = 4 n * 4 channel-chunks * 256 pixel-blocks = 4096; 16 channels/thread.
__global__ __launch_bounds__(256) void k_warp(
    const float* __restrict__ x1, const float* __restrict__ x2,
    const float* __restrict__ flow, float* __restrict__ out)
{
    const int bid   = blockIdx.x;
    const int n     = bid >> 10;
    const int chunk = (bid >> 8) & 3;
    const int t     = threadIdx.x;
    const int p     = ((bid & 255) << 8) | t;
    const int h     = p >> 8, w = p & 255;
    const int np    = (n << 16) | p;

    const float fx1 = flow[np];
    const float fy1 = flow[262144 + np];
    const float fx2 = flow[524288 + np];
    const float fy2 = flow[786432 + np];
    const float S = 255.0f / 512.0f;       // (W-1)/(2W)

    float gxa = (float)w + fx1 * S, gya = (float)h + fy1 * S;
    float gxb = (float)w + fx2 * S, gyb = (float)h + fy2 * S;

    int a00, a01, a10, a11, b00, b01, b10, b11;
    float wa00, wa01, wa10, wa11, wb00, wb01, wb10, wb11;
    {
        float x0f = floorf(gxa), y0f = floorf(gya);
        float wx1 = gxa - x0f, wy1 = gya - y0f;
        float wx0 = 1.0f - wx1, wy0 = 1.0f - wy1;
        int ix0 = (int)x0f, iy0 = (int)y0f;
        int ix1 = ix0 + 1,  iy1 = iy0 + 1;
        bool vx0 = (ix0 >= 0) && (ix0 <= 255), vx1 = (ix1 >= 0) && (ix1 <= 255);
        bool vy0 = (iy0 >= 0) && (iy0 <= 255), vy1 = (iy1 >= 0) && (iy1 <= 255);
        int x0c = min(max(ix0, 0), 255), x1c = min(max(ix1, 0), 255);
        int y0c = min(max(iy0, 0), 255), y1c = min(max(iy1, 0), 255);
        a00 = (y0c << 8) | x0c; a01 = (y0c << 8) | x1c;
        a10 = (y1c << 8) | x0c; a11 = (y1c << 8) | x1c;
        wa00 = wx0 * wy0 * ((vx0 && vy0) ? 1.0f : 0.0f);
        wa01 = wx1 * wy0 * ((vx1 && vy0) ? 1.0f : 0.0f);
        wa10 = wx0 * wy1 * ((vx0 && vy1) ? 1.0f : 0.0f);
        wa11 = wx1 * wy1 * ((vx1 && vy1) ? 1.0f : 0.0f);
    }
    {
        float x0f = floorf(gxb), y0f = floorf(gyb);
        float wx1 = gxb - x0f, wy1 = gyb - y0f;
        float wx0 = 1.0f - wx1, wy0 = 1.0f - wy1;
        int ix0 = (int)x0f, iy0 = (int)y0f;
        int ix1 = ix0 + 1,  iy1 = iy0 + 1;
        bool vx0 = (ix0 >= 0) && (ix0 <= 255), vx1 = (ix1 >= 0) && (ix1 <= 255);
        bool vy0 = (iy0 >= 0) && (iy0 <= 255), vy1 = (iy1 >= 0) && (iy1 <= 255);
        int x0c = min(max(ix0, 0), 255), x1c = min(max(ix1, 0), 255);
        int y0c = min(max(iy0, 0), 255), y1c = min(max(iy1, 0), 255);
        b00 = (y0c << 8) | x0c; b01 = (y0c << 8) | x1c;
        b10 = (y1c << 8) | x0c; b11 = (y1c << 8) | x1c;
        wb00 = wx0 * wy0 * ((vx0 && vy0) ? 1.0f : 0.0f);
        wb01 = wx1 * wy0 * ((vx1 && vy0) ? 1.0f : 0.0f);
        wb10 = wx0 * wy1 * ((vx0 && vy1) ? 1.0f : 0.0f);
        wb11 = wx1 * wy1 * ((vx1 && vy1) ? 1.0f : 0.0f);
    }

    const int c0 = chunk << 4;
    const float* P1 = x1 + (((size_t)(n * 64 + c0)) << 16);
    const float* P2 = x2 + (((size_t)(n * 64 + c0)) << 16);
    float* O1 = out + (((size_t)(n * 64 + c0)) << 16) + p;
    float* O2 = out + 16777216 + (((size_t)(n * 64 + c0)) << 16) + p;

#pragma unroll 4
    for (int c = 0; c < 16; ++c) {
        const size_t base = (size_t)c << 16;
        const float* q1 = P1 + base;
        const float* q2 = P2 + base;
        float sA = wa00 * q1[a00] + wa01 * q1[a01] + wa10 * q1[a10] + wa11 * q1[a11];
        float sB = wb00 * q2[b00] + wb01 * q2[b01] + wb10 * q2[b10] + wb11 * q2[b11];
        O1[base] = sA - q2[p];
        O2[base] = sB - q1[p];
    }
}

extern "C" void kernel_launch(void* const* d_in, const int* in_sizes, int n_in,
                              void* d_out, int out_size, void* d_ws, size_t ws_size,
                              hipStream_t stream) {
    const float* x1  = (const float*)d_in[0];
    const float* x2  = (const float*)d_in[1];
    const float* dww = (const float*)d_in[2];
    const float* dwb = (const float*)d_in[3];
    const float* pww = (const float*)d_in[4];
    float* out = (float*)d_out;

    float* wsf   = (float*)d_ws;
    float* stats = wsf;                       // 1024 floats
    float* flow  = wsf + 1024;                // 4*262144 floats
    float* part  = wsf + 1024 + 1048576;      // 2*8192 floats
    float* y     = out;                       // stage dwconv output in d_out

    k_dwconv<<<8192, 256, 0, stream>>>(x1, x2, dww, dwb, y, part);
    k_stats<<<2, 256, 0, stream>>>(part, stats);
    k_flow<<<256, 256, 0, stream>>>(y, stats, pww, flow);
    k_warp<<<4096, 256, 0, stream>>>(x1, x2, flow, out);
}